// Round 7
// baseline (116.459 us; speedup 1.0000x reference)
//
#include <hip/hip_runtime.h>
#include <math.h>

// Problem constants: B=4, S=2048, D_IN=1024, D_OUT=1024, E=8, K=2
#define TOKENS 8192
#define DIN    1024
#define DOUT   1024
#define NE     8

typedef float vf4 __attribute__((ext_vector_type(4)));

// ---------------- Kernel A: gate + value -> one scalar per token ----------------
// One wave per token: 1024 blocks x 512 threads (8 waves) -> 4 blocks/CU,
// full 32 waves/CU (LDS 32 KB x 4 = 128 <= 160 KB). Stage-major issue
// everywhere so independent memory ops overlap. Output: sv[t] = weighted
// scalar; out_idx[t][0..1] = top-2 expert ids. Only ~96 KB written -> this
// kernel is a pure x-read stream (~39 MB).
__global__ __launch_bounds__(512, 4) void moe_gate(
    const float* __restrict__ x,             // [TOKENS][DIN]
    const float* __restrict__ gate_w,        // [NE][DIN]
    const float* __restrict__ gate_b,        // [NE]
    const float* __restrict__ expert_biases, // [NE]
    const float* __restrict__ expert_w,      // [NE][DOUT][DIN]
    const float* __restrict__ expert_b,      // [NE][DOUT]
    float* __restrict__ sv,                  // [TOKENS] weighted scalar
    float* __restrict__ out_idx) {           // [TOKENS][2] (indices as f32)
  __shared__ float lgate[NE * DIN];  // 32 KB f32 (selection must be f32-exact)

  {
    const vf4* src = (const vf4*)gate_w;
    vf4* dst = (vf4*)lgate;
#pragma unroll
    for (int i = 0; i < 4; ++i)
      dst[threadIdx.x + 512 * i] = src[threadIdx.x + 512 * i];
  }

  const int t    = blockIdx.x * 8 + (threadIdx.x >> 6);  // token == wave id
  const int lane = threadIdx.x & 63;

  // x loads issued before the barrier: HBM latency hides under the barrier drain
  vf4 xa[4];
  const vf4* xr = (const vf4*)(x + (size_t)t * DIN);
#pragma unroll
  for (int i = 0; i < 4; ++i) xa[i] = xr[lane + 64 * i];

  __syncthreads();

  // gate logits, stage-major: per segment issue all 8 experts' LDS reads
  float za[NE];
#pragma unroll
  for (int e = 0; e < NE; ++e) za[e] = 0.f;
#pragma unroll
  for (int i = 0; i < 4; ++i) {
    vf4 w[NE];
#pragma unroll
    for (int e = 0; e < NE; ++e)
      w[e] = ((const vf4*)(lgate + e * DIN))[lane + 64 * i];
#pragma unroll
    for (int e = 0; e < NE; ++e)
      za[e] += xa[i].x * w[e].x + xa[i].y * w[e].y + xa[i].z * w[e].z + xa[i].w * w[e].w;
  }

  // butterfly reduction, stage-major: 8 independent shuffles per stage
#pragma unroll
  for (int off = 32; off > 0; off >>= 1) {
    float tmp[NE];
#pragma unroll
    for (int e = 0; e < NE; ++e) tmp[e] = __shfl_xor(za[e], off, 64);
#pragma unroll
    for (int e = 0; e < NE; ++e) za[e] += tmp[e];
  }
#pragma unroll
  for (int e = 0; e < NE; ++e) za[e] += gate_b[e] + expert_biases[e];

  // top-2 on logits (sigmoid monotone -> identical indices & tie order)
  int e0 = 0; float z0 = za[0];
#pragma unroll
  for (int e = 1; e < NE; ++e) if (za[e] > z0) { z0 = za[e]; e0 = e; }
  int e1 = (e0 == 0) ? 1 : 0; float z1 = za[e1];
#pragma unroll
  for (int e = 0; e < NE; ++e) if (e != e0 && za[e] > z1) { z1 = za[e]; e1 = e; }

  // both expert value rows (64 KB working set, L2-hot) issued together
  const vf4* r0 = (const vf4*)(expert_w + (size_t)e0 * (DOUT * DIN));        // w[e0][0][:]
  const vf4* r1 = (const vf4*)(expert_w + (size_t)e1 * (DOUT * DIN) + DIN);  // w[e1][1][:]
  vf4 wa[4], wb[4];
#pragma unroll
  for (int i = 0; i < 4; ++i) { wa[i] = r0[lane + 64 * i]; wb[i] = r1[lane + 64 * i]; }
  float b0 = expert_b[e0 * DOUT + 0];
  float b1 = expert_b[e1 * DOUT + 1];

  float p0 = 1.f / (1.f + expf(-z0));
  float p1 = 1.f / (1.f + expf(-z1));
  float s  = 1.f / (p0 + p1);
  float w0 = p0 * s, w1 = p1 * s;

  float d0 = 0.f, d1 = 0.f;
#pragma unroll
  for (int i = 0; i < 4; ++i) {
    d0 += xa[i].x * wa[i].x + xa[i].y * wa[i].y + xa[i].z * wa[i].z + xa[i].w * wa[i].w;
    d1 += xa[i].x * wb[i].x + xa[i].y * wb[i].y + xa[i].z * wb[i].z + xa[i].w * wb[i].w;
  }
#pragma unroll
  for (int off = 32; off > 0; off >>= 1) {
    float t0 = __shfl_xor(d0, off, 64);
    float t1 = __shfl_xor(d1, off, 64);
    d0 += t0; d1 += t1;
  }
  d0 += b0; d1 += b1;

  if (lane == 0) {
    sv[t] = d0 * w0 + d1 * w1;
    out_idx[t * 2 + 0] = (float)e0;
    out_idx[t * 2 + 1] = (float)e1;
  }
}

// ---------------- Kernel B: broadcast scalars into full output rows ----------------
// Pure write stream: 33.6 MB at near write-peak. 1024 blocks x 256 threads,
// 8 rows/block, 1 float4/thread/row. Scalar reads are wave-uniform (s_load).
__global__ __launch_bounds__(256, 8) void moe_bcast(
    const float* __restrict__ sv,   // [TOKENS]
    float* __restrict__ out) {      // [TOKENS][DOUT]
  const int rbase = blockIdx.x * 8;
  const int tid = threadIdx.x;
  float v[8];
#pragma unroll
  for (int r = 0; r < 8; ++r) v[r] = sv[rbase + r];
#pragma unroll
  for (int r = 0; r < 8; ++r) {
    vf4 vv = {v[r], v[r], v[r], v[r]};
    ((vf4*)(out + (size_t)(rbase + r) * DOUT))[tid] = vv;
  }
}

extern "C" void kernel_launch(void* const* d_in, const int* in_sizes, int n_in,
                              void* d_out, int out_size, void* d_ws, size_t ws_size,
                              hipStream_t stream) {
  const float* x             = (const float*)d_in[0];
  const float* gate_w        = (const float*)d_in[1];
  const float* gate_b        = (const float*)d_in[2];
  const float* expert_biases = (const float*)d_in[3];
  const float* expert_w      = (const float*)d_in[4];
  const float* expert_b      = (const float*)d_in[5];

  float* out     = (float*)d_out;
  float* out_idx = out + (size_t)TOKENS * DOUT;  // second tuple output, flat-concatenated
  float* sv      = (float*)d_ws;                 // [TOKENS] scratch scalars

  moe_gate<<<dim3(1024), dim3(512), 0, stream>>>(
      x, gate_w, gate_b, expert_biases, expert_w, expert_b, sv, out_idx);
  moe_bcast<<<dim3(1024), dim3(256), 0, stream>>>(sv, out);
}